// Round 1
// baseline (650.379 us; speedup 1.0000x reference)
//
#include <hip/hip_runtime.h>
#include <hip/hip_bf16.h>
#include <math.h>

// Problem constants
#define BB 2
#define NN 4096
#define CC 256
#define HH 8
#define MM 48
#define TT 10000
#define LL 256
#define CHDIM 32
#define HIDD 512
#define ROWS (BB*NN)   // 8192

// ---------------- pe_table = pre_table @ Wpe + bpe  (T x H) ----------------
__global__ void pe_kernel(const float* __restrict__ pre, const float* __restrict__ Wpe,
                          const float* __restrict__ bpe, float* __restrict__ pet) {
    int i = blockIdx.x * blockDim.x + threadIdx.x;   // t*H + h
    if (i >= TT * HH) return;
    int t = i / HH, h = i % HH;
    float s = bpe[h];
    #pragma unroll
    for (int j = 0; j < 5; ++j) s += pre[t * 5 + j] * Wpe[j * HH + h];
    pet[i] = s;
}

// ---------------- LayerNorm over C=256, one block per row ----------------
__global__ __launch_bounds__(256) void ln_kernel(const float* __restrict__ in,
                                                 const float* __restrict__ g,
                                                 const float* __restrict__ b,
                                                 float* __restrict__ out) {
    int row = blockIdx.x;
    int tid = threadIdx.x;
    float v = in[(size_t)row * CC + tid];
    __shared__ float r1[4], r2[4];
    float s = v;
    #pragma unroll
    for (int off = 32; off; off >>= 1) s += __shfl_xor(s, off, 64);
    if ((tid & 63) == 0) r1[tid >> 6] = s;
    __syncthreads();
    float mu = (r1[0] + r1[1] + r1[2] + r1[3]) * (1.0f / 256.0f);
    float d = v - mu;
    float s2 = d * d;
    #pragma unroll
    for (int off = 32; off; off >>= 1) s2 += __shfl_xor(s2, off, 64);
    if ((tid & 63) == 0) r2[tid >> 6] = s2;
    __syncthreads();
    float var = (r2[0] + r2[1] + r2[2] + r2[3]) * (1.0f / 256.0f);
    float rs = rsqrtf(var + 1e-5f);
    out[(size_t)row * CC + tid] = d * rs * g[tid] + b[tid];
}

// ---------------- fp32 tiled GEMM: out = act((A@W + bias)*scale) + residual ----------------
// BM=BN=128, BK=16, 256 threads, 8x8 per thread. M,N multiples of 128; K multiple of 16.
#define BM 128
#define BN 128
#define BKK 16
__global__ __launch_bounds__(256) void gemm_kernel(const float* __restrict__ A,
                                                   const float* __restrict__ W,
                                                   const float* __restrict__ bias,
                                                   float* __restrict__ out,
                                                   int M, int Nn, int K, float scale,
                                                   const float* __restrict__ residual,
                                                   int act) {
    __shared__ float As[BKK][BM];
    __shared__ float Bs[BKK][BN];
    int tid = threadIdx.x;
    int tx = tid % 16, ty = tid / 16;
    int row0 = blockIdx.y * BM, col0 = blockIdx.x * BN;
    float acc[8][8] = {};
    for (int k0 = 0; k0 < K; k0 += BKK) {
        // A tile 128x16
        {
            int m = tid >> 1;
            int kq = (tid & 1) * 8;
            const float* ap = A + (size_t)(row0 + m) * K + k0 + kq;
            float4 a0 = *(const float4*)ap;
            float4 a1 = *(const float4*)(ap + 4);
            As[kq + 0][m] = a0.x; As[kq + 1][m] = a0.y; As[kq + 2][m] = a0.z; As[kq + 3][m] = a0.w;
            As[kq + 4][m] = a1.x; As[kq + 5][m] = a1.y; As[kq + 6][m] = a1.z; As[kq + 7][m] = a1.w;
        }
        // B tile 16x128
        {
            int kk = tid >> 4;
            int nq = (tid & 15) * 8;
            const float* bp = W + (size_t)(k0 + kk) * Nn + col0 + nq;
            *(float4*)&Bs[kk][nq]     = *(const float4*)bp;
            *(float4*)&Bs[kk][nq + 4] = *(const float4*)(bp + 4);
        }
        __syncthreads();
        #pragma unroll
        for (int kk = 0; kk < BKK; ++kk) {
            float a[8], bb[8];
            #pragma unroll
            for (int i = 0; i < 8; ++i) a[i] = As[kk][ty * 8 + i];
            #pragma unroll
            for (int j = 0; j < 8; ++j) bb[j] = Bs[kk][tx * 8 + j];
            #pragma unroll
            for (int i = 0; i < 8; ++i)
                #pragma unroll
                for (int j = 0; j < 8; ++j)
                    acc[i][j] += a[i] * bb[j];
        }
        __syncthreads();
    }
    #pragma unroll
    for (int i = 0; i < 8; ++i) {
        size_t r = row0 + ty * 8 + i;
        #pragma unroll
        for (int jj = 0; jj < 2; ++jj) {
            int cbase = col0 + tx * 8 + jj * 4;
            float4 bv = *(const float4*)&bias[cbase];
            float vout[4];
            float bva[4] = {bv.x, bv.y, bv.z, bv.w};
            #pragma unroll
            for (int j = 0; j < 4; ++j) {
                float v = (acc[i][jj * 4 + j] + bva[j]) * scale;
                if (act == 1) v = 0.5f * v * (1.0f + erff(v * 0.70710678118654752f));
                vout[j] = v;
            }
            if (residual) {
                float4 rv = *(const float4*)&residual[r * Nn + cbase];
                vout[0] += rv.x; vout[1] += rv.y; vout[2] += rv.z; vout[3] += rv.w;
            }
            *(float4*)&out[r * Nn + cbase] = make_float4(vout[0], vout[1], vout[2], vout[3]);
        }
    }
}

// ---------------- cluster attention (fused): one wave per (b,n,h) ----------------
// q: [8192,256] (scaled), kv: [8192,512] col = h*64 + s*32 + ch
__global__ __launch_bounds__(256) void cluster_attn_kernel(
    const float* __restrict__ q, const float* __restrict__ kv,
    const int* __restrict__ member_idx, const int* __restrict__ cluster_mask,
    const int* __restrict__ pe_idx, const float* __restrict__ pet,
    const float* __restrict__ blank_k, const float* __restrict__ blank_v,
    float* __restrict__ outp) {
    __shared__ float s_pa[4][64];
    __shared__ int s_idx[4][48];
    int tid = threadIdx.x;
    int wid = tid >> 6, lane = tid & 63;
    int w = blockIdx.x * 4 + wid;      // (row*8 + h)
    int h = w & 7;
    int row = w >> 3;                  // b*4096 + n
    int b = row >> 12;
    const float* qrow = q + (size_t)row * CC + h * CHDIM;
    float logit = -1e30f;
    if (lane < MM) {
        int idx = member_idx[(size_t)row * MM + lane];
        s_idx[wid][lane] = idx;
        const float* krow = kv + ((size_t)(b * NN + idx)) * 512 + h * 64;
        float d = 0.0f;
        #pragma unroll
        for (int c = 0; c < CHDIM; ++c) d += qrow[c] * krow[c];
        d += pet[(size_t)pe_idx[(size_t)row * MM + lane] * HH + h];
        if (cluster_mask[(size_t)row * MM + lane] == 0) d -= 100.0f;
        logit = d;
    } else if (lane == MM) {
        float d = 0.0f;
        #pragma unroll
        for (int c = 0; c < CHDIM; ++c) d += qrow[c] * blank_k[h * CHDIM + c];
        logit = d;
    }
    float mx = logit;
    #pragma unroll
    for (int off = 32; off; off >>= 1) mx = fmaxf(mx, __shfl_xor(mx, off, 64));
    float e = expf(logit - mx);        // lanes > 48 -> 0
    float ssum = e;
    #pragma unroll
    for (int off = 32; off; off >>= 1) ssum += __shfl_xor(ssum, off, 64);
    s_pa[wid][lane] = e / ssum;
    // same-wave LDS RAW: compiler inserts lgkmcnt
    if (lane < CHDIM) {
        int c = lane;
        float accv = s_pa[wid][MM] * blank_v[h * CHDIM + c];
        for (int m = 0; m < MM; ++m) {
            accv += s_pa[wid][m] * kv[((size_t)(b * NN + s_idx[wid][m])) * 512 + h * 64 + 32 + c];
        }
        outp[(size_t)row * CC + h * CHDIM + c] = accv;
    }
}

// ---------------- cross attention (fused): K/V in LDS, one thread per query row ----------------
__global__ __launch_bounds__(256) void cross_attn_kernel(
    const float* __restrict__ xq,   // [8192,256] scaled
    const float* __restrict__ xk,   // [512,256]
    const float* __restrict__ xv,   // [512,256]
    float* __restrict__ o) {        // [8192,256]
    __shared__ float ks[LL][CHDIM];
    __shared__ float vs[LL][CHDIM];
    int tid = threadIdx.x;
    int tile = blockIdx.x, h = blockIdx.y, b = blockIdx.z;
    for (int i = tid; i < LL * 8; i += 256) {
        int l = i >> 3;
        int cq = (i & 7) * 4;
        *(float4*)&ks[l][cq] = *(const float4*)&xk[((size_t)(b * LL + l)) * CC + h * CHDIM + cq];
        *(float4*)&vs[l][cq] = *(const float4*)&xv[((size_t)(b * LL + l)) * CC + h * CHDIM + cq];
    }
    __syncthreads();
    int n = tile * 256 + tid;
    size_t qoff = ((size_t)(b * NN + n)) * CC + h * CHDIM;
    float qr[CHDIM];
    #pragma unroll
    for (int c = 0; c < CHDIM; ++c) qr[c] = xq[qoff + c];
    float mx = -1e30f;
    for (int l = 0; l < LL; ++l) {
        float d = 0.0f;
        #pragma unroll
        for (int c = 0; c < CHDIM; ++c) d += qr[c] * ks[l][c];
        mx = fmaxf(mx, d);
    }
    float ssum = 0.0f;
    float acc[CHDIM] = {0.0f};
    for (int l = 0; l < LL; ++l) {
        float d = 0.0f;
        #pragma unroll
        for (int c = 0; c < CHDIM; ++c) d += qr[c] * ks[l][c];
        float e = expf(d - mx);
        ssum += e;
        #pragma unroll
        for (int c = 0; c < CHDIM; ++c) acc[c] += e * vs[l][c];
    }
    float inv = 1.0f / ssum;
    #pragma unroll
    for (int c = 0; c < CHDIM; ++c) o[qoff + c] = acc[c] * inv;
}

extern "C" void kernel_launch(void* const* d_in, const int* in_sizes, int n_in,
                              void* d_out, int out_size, void* d_ws, size_t ws_size,
                              hipStream_t stream) {
    const float* feat        = (const float*)d_in[0];
    const float* memory      = (const float*)d_in[1];
    const int*   member_idx  = (const int*)d_in[2];
    const int*   cluster_mask= (const int*)d_in[3];
    const int*   pe_idx      = (const int*)d_in[4];
    // d_in[5] global_attn == 0 (asserted in reference)
    const float* pre_table   = (const float*)d_in[6];
    const float* Wq    = (const float*)d_in[7];
    const float* bq    = (const float*)d_in[8];
    const float* Wkv   = (const float*)d_in[9];
    const float* bkv   = (const float*)d_in[10];
    const float* blank_k = (const float*)d_in[11];
    const float* blank_v = (const float*)d_in[12];
    const float* Wpe   = (const float*)d_in[13];
    const float* bpe   = (const float*)d_in[14];
    const float* Wproj = (const float*)d_in[15];
    const float* bproj = (const float*)d_in[16];
    const float* g1    = (const float*)d_in[17];
    const float* be1   = (const float*)d_in[18];
    const float* g2    = (const float*)d_in[19];
    const float* be2   = (const float*)d_in[20];
    const float* xWq   = (const float*)d_in[21];
    const float* xbq   = (const float*)d_in[22];
    const float* xWk   = (const float*)d_in[23];
    const float* xbk   = (const float*)d_in[24];
    const float* xWv   = (const float*)d_in[25];
    const float* xbv   = (const float*)d_in[26];
    const float* xWo   = (const float*)d_in[27];
    const float* xbo   = (const float*)d_in[28];
    const float* xg    = (const float*)d_in[29];
    const float* xbe   = (const float*)d_in[30];
    const float* W1    = (const float*)d_in[31];
    const float* bf1   = (const float*)d_in[32];
    const float* W2    = (const float*)d_in[33];
    const float* bf2   = (const float*)d_in[34];
    float* out = (float*)d_out;
    float* ws  = (float*)d_ws;

    // workspace layout (floats): total ~12.93M floats (~52 MB)
    float* bufA = ws;                  // 2M  (x1 / t2 / t3)
    float* bufB = ws + 2097152;        // 2M  (q / xq)
    float* bufC = ws + 4194304;        // 4M  (kv / hidden)
    float* bufD = ws + 8388608;        // 2M  (attnout / o)
    float* bufE = ws + 10485760;       // 2M  (feat1)
    float* xk   = ws + 12582912;       // 131072
    float* xv   = xk + 131072;         // 131072
    float* pet  = xv + 131072;         // 80000

    const float scale = 0.17677669529663689f; // 1/sqrt(32)

    // pe_table
    pe_kernel<<<(TT * HH + 255) / 256, 256, 0, stream>>>(pre_table, Wpe, bpe, pet);
    // x1 = LN(feat)
    ln_kernel<<<ROWS, 256, 0, stream>>>(feat, g1, be1, bufA);
    // q = (x1 @ Wq + bq) * scale
    gemm_kernel<<<dim3(CC / BN, ROWS / BM), 256, 0, stream>>>(bufA, Wq, bq, bufB, ROWS, CC, CC, scale, nullptr, 0);
    // kv = x1 @ Wkv + bkv
    gemm_kernel<<<dim3(512 / BN, ROWS / BM), 256, 0, stream>>>(bufA, Wkv, bkv, bufC, ROWS, 512, CC, 1.0f, nullptr, 0);
    // cluster attention -> bufD
    cluster_attn_kernel<<<ROWS * HH / 4, 256, 0, stream>>>(bufB, bufC, member_idx, cluster_mask, pe_idx, pet, blank_k, blank_v, bufD);
    // feat1 = feat + attnout @ Wproj + bproj
    gemm_kernel<<<dim3(CC / BN, ROWS / BM), 256, 0, stream>>>(bufD, Wproj, bproj, bufE, ROWS, CC, CC, 1.0f, feat, 0);
    // t2 = LN(feat1)
    ln_kernel<<<ROWS, 256, 0, stream>>>(bufE, xg, xbe, bufA);
    // xq = (t2 @ xWq + xbq) * scale
    gemm_kernel<<<dim3(CC / BN, ROWS / BM), 256, 0, stream>>>(bufA, xWq, xbq, bufB, ROWS, CC, CC, scale, nullptr, 0);
    // xk/xv from memory
    gemm_kernel<<<dim3(CC / BN, (BB * LL) / BM), 256, 0, stream>>>(memory, xWk, xbk, xk, BB * LL, CC, CC, 1.0f, nullptr, 0);
    gemm_kernel<<<dim3(CC / BN, (BB * LL) / BM), 256, 0, stream>>>(memory, xWv, xbv, xv, BB * LL, CC, CC, 1.0f, nullptr, 0);
    // cross attention -> bufD
    cross_attn_kernel<<<dim3(NN / 256, HH, BB), 256, 0, stream>>>(bufB, xk, xv, bufD);
    // feat2 = feat1 + o @ xWo + xbo   (feat2 stored in d_out)
    gemm_kernel<<<dim3(CC / BN, ROWS / BM), 256, 0, stream>>>(bufD, xWo, xbo, out, ROWS, CC, CC, 1.0f, bufE, 0);
    // t3 = LN(feat2)
    ln_kernel<<<ROWS, 256, 0, stream>>>(out, g2, be2, bufA);
    // h = gelu(t3 @ W1 + bf1)
    gemm_kernel<<<dim3(HIDD / BN, ROWS / BM), 256, 0, stream>>>(bufA, W1, bf1, bufC, ROWS, HIDD, CC, 1.0f, nullptr, 1);
    // out = feat2 + h @ W2 + bf2
    gemm_kernel<<<dim3(CC / BN, ROWS / BM), 256, 0, stream>>>(bufC, W2, bf2, out, ROWS, CC, HIDD, 1.0f, out, 0);
}